// Round 3
// baseline (182.840 us; speedup 1.0000x reference)
//
#include <hip/hip_runtime.h>
#include <hip/hip_bf16.h>

using u16 = unsigned short;
using u32 = unsigned int;

typedef __bf16 bf16x8 __attribute__((ext_vector_type(8)));
typedef float f32x4 __attribute__((ext_vector_type(4)));

__device__ __forceinline__ u16 f2bf(float f) {
  union { float f; u32 u; } c; c.f = f;
  u32 u = c.u;
  u32 r = u + 0x7fffu + ((u >> 16) & 1u);   // RNE
  return (u16)(r >> 16);
}
__device__ __forceinline__ u32 pack2(float a, float b) {
  return (u32)f2bf(a) | ((u32)f2bf(b) << 16);
}

constexpr int Bb  = 64;    // graphs
constexpr int L   = 1024;  // nodes/graph
constexpr int IN  = 128;
constexpr int OUT = 128;
constexpr int FLR = 64;
constexpr int N   = Bb * L;

// ---------------------------------------------------------------------------
// k_pack: one-time weight repack into MFMA B-fragment order (bf16).
// UNCHANGED this round.
// ---------------------------------------------------------------------------
__global__ __launch_bounds__(256) void k_pack(
    const float* __restrict__ Wout, const float* __restrict__ Wh,
    u16* __restrict__ Bp, u16* __restrict__ Whp)
{
  const int blk = blockIdx.x;
  if (blk < 16) {
    int t2 = blk * 256 + threadIdx.x;    // 0..4095 frag-lanes
    int lane = t2 & 63, kstep = (t2 >> 6) & 7, ntile = t2 >> 9;
    int n  = ntile * 16 + (lane & 15);
    int kb = kstep * 32 + (lane >> 4) * 8;
    u16* dst = Bp + (size_t)t2 * 8;
#pragma unroll
    for (int j = 0; j < 8; ++j) dst[j] = f2bf(Wout[(kb + j) * OUT + n]);
  } else {
#pragma unroll
    for (int i = 0; i < 4; ++i) {
      int t2 = i * 256 + threadIdx.x;    // 0..1023 frag-lanes
      int l = t2 & 63, ks = (t2 >> 6) & 3, nt = t2 >> 8;
      int kb = ks * 32 + (l >> 4) * 8;
      u16* dst = Whp + (size_t)t2 * 8;
#pragma unroll
      for (int j = 0; j < 8; ++j)
        dst[j] = f2bf(Wh[(size_t)(kb + j) * FLR + nt * 16 + (l & 15)]);
    }
  }
}

// ---------------------------------------------------------------------------
// k_sh — DIAGNOSTIC ROUND: grid is 2048 blocks; blocks >=1024 redo blocks
// 0..1023 (blk = blockIdx.x & 1023). All duplicate writes are bit-identical
// words to identical addresses (pure function of read-only inputs) -> benign
// race, output unchanged. Purpose: the dispatch now runs ~2x its true
// duration, so it surfaces in the rocprof top-5 and exposes its counters
// (VALUBusy / MfmaUtil / hbm_pct / FETCH / occupancy), which have never been
// observed — two consecutive theory-miss rounds mean we buy data, not guesses.
// Kernel body is otherwise byte-identical to round 2.
// ---------------------------------------------------------------------------
__global__ __launch_bounds__(256) void k_sh(
    const float* __restrict__ x, const float* __restrict__ Ws, const float* __restrict__ bs,
    const u16* __restrict__ Whp, const float* __restrict__ bh,
    float* __restrict__ s_buf, u16* __restrict__ h_buf)
{
  __shared__ alignas(16) u16 whl[128 * 64];   // 16 KB: Wh bf16 frags

  const int tid = threadIdx.x;
  // ---- stage packed Wh -> LDS (fully coalesced; hides under loop 1)
  {
    const uint4* __restrict__ src = (const uint4*)Whp;
    uint4* dstl = (uint4*)whl;
#pragma unroll
    for (int i = 0; i < 4; ++i) {
      int idx = i * 256 + tid;
      dstl[idx] = src[idx];
    }
  }

  const int blk = blockIdx.x & 1023;       // <-- duplicate-work mapping
  const int lane = tid & 63;
  const int w = __builtin_amdgcn_readfirstlane(tid >> 6);
  const int mb = blk * 64 + w * 16;        // m-tile base node
  const int col = lane & 15;
  const int kq  = lane >> 4;               // 0..3
  const int mrow = mb + col;               // this lane's A row

  const float* xr = x + (size_t)mrow * IN;

  // ---- load x A-frags (fp32->bf16) + accumulate s partials in fp32
  float sp0 = 0.f, sp1 = 0.f, sp2 = 0.f, sp3 = 0.f;
  bf16x8 a[4];
#pragma unroll
  for (int ks = 0; ks < 4; ++ks) {
    float4 xa = *(const float4*)(xr + ks * 32 + kq * 8);
    float4 xb = *(const float4*)(xr + ks * 32 + kq * 8 + 4);
    float xf[8] = {xa.x, xa.y, xa.z, xa.w, xb.x, xb.y, xb.z, xb.w};
#pragma unroll
    for (int j = 0; j < 8; ++j) {
      const float4 wsr = *(const float4*)(Ws + (size_t)(ks * 32 + kq * 8 + j) * 4);
      sp0 = fmaf(xf[j], wsr.x, sp0);
      sp1 = fmaf(xf[j], wsr.y, sp1);
      sp2 = fmaf(xf[j], wsr.z, sp2);
      sp3 = fmaf(xf[j], wsr.w, sp3);
    }
    union { __hip_bfloat162 h2[4]; bf16x8 v; } cv;
    cv.h2[0] = __float22bfloat162_rn(float2{xf[0], xf[1]});
    cv.h2[1] = __float22bfloat162_rn(float2{xf[2], xf[3]});
    cv.h2[2] = __float22bfloat162_rn(float2{xf[4], xf[5]});
    cv.h2[3] = __float22bfloat162_rn(float2{xf[6], xf[7]});
    a[ks] = cv.v;
  }

  // ---- s reduce + store (fp32) — before the barrier, independent of whl
  sp0 += __shfl_xor(sp0, 16, 64); sp0 += __shfl_xor(sp0, 32, 64);
  sp1 += __shfl_xor(sp1, 16, 64); sp1 += __shfl_xor(sp1, 32, 64);
  sp2 += __shfl_xor(sp2, 16, 64); sp2 += __shfl_xor(sp2, 32, 64);
  sp3 += __shfl_xor(sp3, 16, 64); sp3 += __shfl_xor(sp3, 32, 64);
  if (kq == 0) {
    float4 sv;
    sv.x = sp0 + bs[0]; sv.y = sp1 + bs[1];
    sv.z = sp2 + bs[2]; sv.w = sp3 + bs[3];
    *(float4*)(s_buf + (size_t)mrow * 4) = sv;
  }

  __syncthreads();   // whl ready

  // ---- h GEMM: 4 n-tiles x 4 k-steps; B-frag = 1 ds_read_b128 each
  f32x4 acc[4];
#pragma unroll
  for (int nt = 0; nt < 4; ++nt) acc[nt] = f32x4{0.f, 0.f, 0.f, 0.f};

  const bf16x8* __restrict__ wf = (const bf16x8*)whl;
#pragma unroll
  for (int nt = 0; nt < 4; ++nt) {
#pragma unroll
    for (int ks = 0; ks < 4; ++ks) {
      acc[nt] = __builtin_amdgcn_mfma_f32_16x16x32_bf16(
          a[ks], wf[(nt * 4 + ks) * 64 + lane], acc[nt], 0, 0, 0);
    }
  }

  // ---- h epilogue: bias + bf16 store (C-layout: col=lane&15, row=kq*4+r)
#pragma unroll
  for (int nt = 0; nt < 4; ++nt) {
    float bias = bh[nt * 16 + col];
#pragma unroll
    for (int r = 0; r < 4; ++r) {
      float v = acc[nt][r] + bias;
      h_buf[(size_t)(mb + kq * 4 + r) * FLR + nt * 16 + col] = f2bf(v);
    }
  }
}

// ---------------------------------------------------------------------------
// k_fused: knn select + aggregate (into LDS) + output GEMM, one block per
// 64 nodes of one graph (512 threads = 8 waves). UNCHANGED this round.
// ---------------------------------------------------------------------------
__global__ __launch_bounds__(512) void k_fused(
    const float* __restrict__ s_buf, const u16* __restrict__ h_buf,
    const float* __restrict__ x, const u16* __restrict__ Bp,
    const float* __restrict__ bout, float* __restrict__ out)
{
  __shared__ alignas(16) float lists[8 * 64 * 17];   // 34.8 KB; later aliased as agg
  __shared__ float fk[64 * 17];                      // final 16 keys per node
  u16* agg_lds = (u16*)lists;                        // [64][136] bf16, stride 136

  const int lane = threadIdx.x & 63;
  const int w = __builtin_amdgcn_readfirstlane(threadIdx.x >> 6);
  const int g = blockIdx.y;
  const int nb0 = blockIdx.x * 64;
  const int node = g * L + nb0 + lane;

  const float4 si = *(const float4*)(s_buf + (size_t)node * 4);
  const float4* __restrict__ sg = (const float4*)(s_buf + (size_t)g * L * 4);
  const int jb = __builtin_amdgcn_readfirstlane(w * 128);

  float b[16];
#pragma unroll
  for (int k = 0; k < 16; ++k) b[k] = 3.0e38f;

#pragma unroll 4
  for (int j = 0; j < 128; ++j) {
    float4 sj = sg[jb + j];
    float dx = si.x - sj.x, dy = si.y - sj.y;
    float dz = si.z - sj.z, dw2 = si.w - sj.w;
    float d2 = fmaf(dw2, dw2, fmaf(dz, dz, fmaf(dy, dy, dx * dx)));
    u32 db = __float_as_uint(d2);
    float key = __uint_as_float((db & 0xFFFFFC00u) | (u32)(jb + j));
#pragma unroll
    for (int k = 15; k >= 1; --k) b[k] = __builtin_amdgcn_fmed3f(key, b[k - 1], b[k]);
    b[0] = fminf(key, b[0]);
  }

#pragma unroll
  for (int k = 0; k < 16; ++k) lists[(w * 64 + lane) * 17 + k] = b[k];
  __syncthreads();

  float c[16];
  if (w < 4) {
#pragma unroll
    for (int i = 0; i < 16; ++i)
      c[i] = fminf(b[i], lists[((w + 4) * 64 + lane) * 17 + (15 - i)]);
#pragma unroll
    for (int dd = 8; dd >= 1; dd >>= 1) {
#pragma unroll
      for (int i = 0; i < 16; ++i) {
        if ((i & dd) == 0) {
          float lo = fminf(c[i], c[i | dd]);
          float hi = fmaxf(c[i], c[i | dd]);
          c[i] = lo; c[i | dd] = hi;
        }
      }
    }
#pragma unroll
    for (int k = 0; k < 16; ++k) lists[(w * 64 + lane) * 17 + k] = c[k];
  }
  __syncthreads();
  if (w < 2) {
#pragma unroll
    for (int i = 0; i < 16; ++i)
      c[i] = fminf(c[i], lists[((w + 2) * 64 + lane) * 17 + (15 - i)]);
#pragma unroll
    for (int dd = 8; dd >= 1; dd >>= 1) {
#pragma unroll
      for (int i = 0; i < 16; ++i) {
        if ((i & dd) == 0) {
          float lo = fminf(c[i], c[i | dd]);
          float hi = fmaxf(c[i], c[i | dd]);
          c[i] = lo; c[i | dd] = hi;
        }
      }
    }
#pragma unroll
    for (int k = 0; k < 16; ++k) lists[(w * 64 + lane) * 17 + k] = c[k];
  }
  __syncthreads();
  if (w == 0) {
#pragma unroll
    for (int i = 0; i < 16; ++i) {
      float o = lists[(64 + lane) * 17 + (15 - i)];
      fk[lane * 17 + i] = fminf(c[i], o);
    }
  }
  __syncthreads();        // fk ready; lists[] now dead -> reuse as agg_lds

  const int q  = lane & 7;
  const int nb = lane >> 3;
  const u16* __restrict__ hg = h_buf + (size_t)g * L * FLR;

#pragma unroll 2
  for (int tt = 0; tt < 8; ++tt) {
    const int nodeL = w * 8 + tt;
    float k1 = fk[nodeL * 17 + nb];
    float k2 = fk[nodeL * 17 + 8 + nb];
    u32 u1 = __float_as_uint(k1), u2 = __float_as_uint(k2);
    float w1 = __expf(-10.0f * __uint_as_float(u1 & 0xFFFFFC00u));
    float w2 = __expf(-10.0f * __uint_as_float(u2 & 0xFFFFFC00u));
    const uint4 a  = ((const uint4*)(hg + (size_t)(u1 & 1023u) * FLR))[q];
    const uint4 b4 = ((const uint4*)(hg + (size_t)(u2 & 1023u) * FLR))[q];
    u32 pa[4] = {a.x, a.y, a.z, a.w};
    u32 pb[4] = {b4.x, b4.y, b4.z, b4.w};
    float m[8], xx[8];
#pragma unroll
    for (int d = 0; d < 4; ++d) {
      float a0 = __uint_as_float(pa[d] << 16) * w1;
      float a1 = __uint_as_float(pa[d] & 0xFFFF0000u) * w1;
      float b0 = __uint_as_float(pb[d] << 16) * w2;
      float b1 = __uint_as_float(pb[d] & 0xFFFF0000u) * w2;
      m[2 * d]     = a0 + b0;  xx[2 * d]     = fmaxf(a0, b0);
      m[2 * d + 1] = a1 + b1;  xx[2 * d + 1] = fmaxf(a1, b1);
    }
#pragma unroll
    for (int mask = 8; mask <= 32; mask <<= 1) {
#pragma unroll
      for (int jj = 0; jj < 8; ++jj) m[jj] += __shfl_xor(m[jj], mask, 64);
#pragma unroll
      for (int jj = 0; jj < 8; ++jj) xx[jj] = fmaxf(xx[jj], __shfl_xor(xx[jj], mask, 64));
    }
    if (nb == 0) {
      uint4 o;
      o.x = pack2(m[0] * 0.0625f, m[1] * 0.0625f);
      o.y = pack2(m[2] * 0.0625f, m[3] * 0.0625f);
      o.z = pack2(m[4] * 0.0625f, m[5] * 0.0625f);
      o.w = pack2(m[6] * 0.0625f, m[7] * 0.0625f);
      *(uint4*)(&agg_lds[nodeL * 136 + q * 8]) = o;
    } else if (nb == 1) {
      uint4 o;
      o.x = pack2(xx[0], xx[1]); o.y = pack2(xx[2], xx[3]);
      o.z = pack2(xx[4], xx[5]); o.w = pack2(xx[6], xx[7]);
      *(uint4*)(&agg_lds[nodeL * 136 + FLR + q * 8]) = o;
    }
  }
  __syncthreads();

  const int mt  = w & 3;
  const int ntb = (w >> 2) * 4;
  const int rowL = mt * 16 + (lane & 15);
  const int grow = g * L + nb0 + rowL;
  const int kq = (lane >> 4) * 8;

  f32x4 acc[4];
#pragma unroll
  for (int nt = 0; nt < 4; ++nt) acc[nt] = f32x4{0.f, 0.f, 0.f, 0.f};

  const float* xr = x + (size_t)grow * IN;
  const bf16x8* __restrict__ bp = (const bf16x8*)Bp;

#pragma unroll
  for (int ks = 0; ks < 8; ++ks) {
    bf16x8 a;
    if (ks < 4) {
      float4 xa = *(const float4*)(xr + ks * 32 + kq);
      float4 xb = *(const float4*)(xr + ks * 32 + kq + 4);
      union { __hip_bfloat162 h2[4]; bf16x8 v; } cv;
      cv.h2[0] = __float22bfloat162_rn(float2{xa.x, xa.y});
      cv.h2[1] = __float22bfloat162_rn(float2{xa.z, xa.w});
      cv.h2[2] = __float22bfloat162_rn(float2{xb.x, xb.y});
      cv.h2[3] = __float22bfloat162_rn(float2{xb.z, xb.w});
      a = cv.v;
    } else {
      a = *(const bf16x8*)(&agg_lds[rowL * 136 + (ks - 4) * 32 + kq]);
    }
#pragma unroll
    for (int nt = 0; nt < 4; ++nt) {
      bf16x8 bb = bp[((ntb + nt) * 8 + ks) * 64 + lane];
      acc[nt] = __builtin_amdgcn_mfma_f32_16x16x32_bf16(a, bb, acc[nt], 0, 0, 0);
    }
  }

  const int rbase = (lane >> 4) * 4;
  const int col = lane & 15;
  const int mrow = g * L + nb0 + mt * 16;
#pragma unroll
  for (int nt = 0; nt < 4; ++nt) {
    float bias = bout[(ntb + nt) * 16 + col];
#pragma unroll
    for (int r = 0; r < 4; ++r) {
      float v = acc[nt][r] + bias;
      out[(size_t)(mrow + rbase + r) * OUT + (ntb + nt) * 16 + col] = fmaxf(v, 0.0f);
    }
  }
}

extern "C" void kernel_launch(void* const* d_in, const int* in_sizes, int n_in,
                              void* d_out, int out_size, void* d_ws, size_t ws_size,
                              hipStream_t stream) {
  const float* x    = (const float*)d_in[0];
  const float* Ws   = (const float*)d_in[1];
  const float* bs   = (const float*)d_in[2];
  const float* Wh   = (const float*)d_in[3];
  const float* bh   = (const float*)d_in[4];
  const float* Wout = (const float*)d_in[5];
  const float* bout = (const float*)d_in[6];
  float* out = (float*)d_out;

  char* ws = (char*)d_ws;
  float* s_buf = (float*)ws;                                     // 1 MiB
  u16*   h_buf = (u16*)(ws + (1 << 20));                         // 8 MiB
  u16*   Bp    = (u16*)(ws + (1 << 20) + (8 << 20));             // 64 KiB
  u16*   Whp   = (u16*)(ws + (1 << 20) + (8 << 20) + (64 << 10)); // 16 KiB

  k_pack<<<17, 256, 0, stream>>>(Wout, Wh, Bp, Whp);
  // DIAGNOSTIC: 2x grid, duplicated work (blk = blockIdx.x & 1023) to surface
  // k_sh in the rocprof top-5. Output is identical (benign identical-write race).
  k_sh<<<2048, 256, 0, stream>>>(x, Ws, bs, Whp, bh, s_buf, h_buf);
  dim3 gknn(L / 64, Bb);
  k_fused<<<gknn, 512, 0, stream>>>(s_buf, h_buf, x, Bp, bout, out);
}

// Round 5
// 158.847 us; speedup vs baseline: 1.1510x; 1.1510x over previous
//
#include <hip/hip_runtime.h>
#include <hip/hip_bf16.h>

using u16 = unsigned short;
using u32 = unsigned int;

typedef __bf16 bf16x8 __attribute__((ext_vector_type(8)));
typedef float f32x4 __attribute__((ext_vector_type(4)));

__device__ __forceinline__ u16 f2bf(float f) {
  union { float f; u32 u; } c; c.f = f;
  u32 u = c.u;
  u32 r = u + 0x7fffu + ((u >> 16) & 1u);   // RNE
  return (u16)(r >> 16);
}
__device__ __forceinline__ u32 pack2(float a, float b) {
  return (u32)f2bf(a) | ((u32)f2bf(b) << 16);
}

constexpr int Bb  = 64;    // graphs
constexpr int L   = 1024;  // nodes/graph
constexpr int IN  = 128;
constexpr int OUT = 128;
constexpr int FLR = 64;
constexpr int N   = Bb * L;

// ---------------------------------------------------------------------------
// k_pack: one-time weight repack into MFMA B-fragment order (bf16). UNCHANGED.
// ---------------------------------------------------------------------------
__global__ __launch_bounds__(256) void k_pack(
    const float* __restrict__ Wout, const float* __restrict__ Wh,
    u16* __restrict__ Bp, u16* __restrict__ Whp)
{
  const int blk = blockIdx.x;
  if (blk < 16) {
    int t2 = blk * 256 + threadIdx.x;    // 0..4095 frag-lanes
    int lane = t2 & 63, kstep = (t2 >> 6) & 7, ntile = t2 >> 9;
    int n  = ntile * 16 + (lane & 15);
    int kb = kstep * 32 + (lane >> 4) * 8;
    u16* dst = Bp + (size_t)t2 * 8;
#pragma unroll
    for (int j = 0; j < 8; ++j) dst[j] = f2bf(Wout[(kb + j) * OUT + n]);
  } else {
#pragma unroll
    for (int i = 0; i < 4; ++i) {
      int t2 = i * 256 + threadIdx.x;    // 0..1023 frag-lanes
      int l = t2 & 63, ks = (t2 >> 6) & 3, nt = t2 >> 8;
      int kb = ks * 32 + (l >> 4) * 8;
      u16* dst = Whp + (size_t)t2 * 8;
#pragma unroll
      for (int j = 0; j < 8; ++j)
        dst[j] = f2bf(Wh[(size_t)(kb + j) * FLR + nt * 16 + (l & 15)]);
    }
  }
}

// ---------------------------------------------------------------------------
// k_sh: h = x@Wh+bh via MFMA with LDS-staged pre-packed B-frags; s = x@Ws+bs
// fp32. Stores the bf16 x A-frags to xbf (if provided) so k_fused's output
// GEMM skips the fp32 x reload + conversion. UNCHANGED from round 4.
// ---------------------------------------------------------------------------
__global__ __launch_bounds__(256) void k_sh(
    const float* __restrict__ x, const float* __restrict__ Ws, const float* __restrict__ bs,
    const u16* __restrict__ Whp, const float* __restrict__ bh,
    float* __restrict__ s_buf, u16* __restrict__ h_buf, u16* __restrict__ xbf)
{
  __shared__ alignas(16) u16 whl[128 * 64];   // 16 KB: Wh bf16 frags

  const int tid = threadIdx.x;
  // ---- stage packed Wh -> LDS (fully coalesced; hides under loop 1)
  {
    const uint4* __restrict__ src = (const uint4*)Whp;
    uint4* dstl = (uint4*)whl;
#pragma unroll
    for (int i = 0; i < 4; ++i) {
      int idx = i * 256 + tid;
      dstl[idx] = src[idx];
    }
  }

  const int blk = blockIdx.x;
  const int lane = tid & 63;
  const int w = __builtin_amdgcn_readfirstlane(tid >> 6);
  const int mb = blk * 64 + w * 16;        // m-tile base node
  const int col = lane & 15;
  const int kq  = lane >> 4;               // 0..3
  const int mrow = mb + col;               // this lane's A row

  const float* xr = x + (size_t)mrow * IN;

  // ---- load x A-frags (fp32->bf16) + accumulate s partials in fp32
  float sp0 = 0.f, sp1 = 0.f, sp2 = 0.f, sp3 = 0.f;
  bf16x8 a[4];
#pragma unroll
  for (int ks = 0; ks < 4; ++ks) {
    float4 xa = *(const float4*)(xr + ks * 32 + kq * 8);
    float4 xb = *(const float4*)(xr + ks * 32 + kq * 8 + 4);
    float xf[8] = {xa.x, xa.y, xa.z, xa.w, xb.x, xb.y, xb.z, xb.w};
#pragma unroll
    for (int j = 0; j < 8; ++j) {
      const float4 wsr = *(const float4*)(Ws + (size_t)(ks * 32 + kq * 8 + j) * 4);
      sp0 = fmaf(xf[j], wsr.x, sp0);
      sp1 = fmaf(xf[j], wsr.y, sp1);
      sp2 = fmaf(xf[j], wsr.z, sp2);
      sp3 = fmaf(xf[j], wsr.w, sp3);
    }
    union { __hip_bfloat162 h2[4]; bf16x8 v; } cv;
    cv.h2[0] = __float22bfloat162_rn(float2{xf[0], xf[1]});
    cv.h2[1] = __float22bfloat162_rn(float2{xf[2], xf[3]});
    cv.h2[2] = __float22bfloat162_rn(float2{xf[4], xf[5]});
    cv.h2[3] = __float22bfloat162_rn(float2{xf[6], xf[7]});
    a[ks] = cv.v;
  }

  // ---- dump A-frags for k_fused's GEMM (frag slot = (tile*4+ks)*64+lane)
  if (xbf) {
#pragma unroll
    for (int ks = 0; ks < 4; ++ks)
      *(bf16x8*)(xbf + (((size_t)(blk * 4 + w) * 4 + ks) * 64 + lane) * 8) = a[ks];
  }

  // ---- s reduce + store (fp32)
  sp0 += __shfl_xor(sp0, 16, 64); sp0 += __shfl_xor(sp0, 32, 64);
  sp1 += __shfl_xor(sp1, 16, 64); sp1 += __shfl_xor(sp1, 32, 64);
  sp2 += __shfl_xor(sp2, 16, 64); sp2 += __shfl_xor(sp2, 32, 64);
  sp3 += __shfl_xor(sp3, 16, 64); sp3 += __shfl_xor(sp3, 32, 64);
  if (kq == 0) {
    float4 sv;
    sv.x = sp0 + bs[0]; sv.y = sp1 + bs[1];
    sv.z = sp2 + bs[2]; sv.w = sp3 + bs[3];
    *(float4*)(s_buf + (size_t)mrow * 4) = sv;
  }

  __syncthreads();   // whl ready

  // ---- h GEMM: 4 n-tiles x 4 k-steps; B-frag = 1 ds_read_b128 each
  f32x4 acc[4];
#pragma unroll
  for (int nt = 0; nt < 4; ++nt) acc[nt] = f32x4{0.f, 0.f, 0.f, 0.f};

  const bf16x8* __restrict__ wf = (const bf16x8*)whl;
#pragma unroll
  for (int nt = 0; nt < 4; ++nt) {
#pragma unroll
    for (int ks = 0; ks < 4; ++ks) {
      acc[nt] = __builtin_amdgcn_mfma_f32_16x16x32_bf16(
          a[ks], wf[(nt * 4 + ks) * 64 + lane], acc[nt], 0, 0, 0);
    }
  }

  // ---- h epilogue: bias + bf16 store (C-layout: col=lane&15, row=kq*4+r)
#pragma unroll
  for (int nt = 0; nt < 4; ++nt) {
    float bias = bh[nt * 16 + col];
#pragma unroll
    for (int r = 0; r < 4; ++r) {
      float v = acc[nt][r] + bias;
      h_buf[(size_t)(mb + kq * 4 + r) * FLR + nt * 16 + col] = f2bf(v);
    }
  }
}

// ---------------------------------------------------------------------------
// k_fused: knn select + aggregate + output GEMM.
// ROUND-5 FIX: wk was carved at lists+8192, but lists has only 8704 floats —
// wk's 1088 floats overran into fk and corrupted the selected keys (absmax
// 0.637 fail). wk now sits at lists+4608 (bytes 18432..22784): dead region
// at write time (last read two barriers earlier), no overlap with the w==0
// phase reads [1088,2176), fk, or agg_lds bytes [0,17408).
// ---------------------------------------------------------------------------
__global__ __launch_bounds__(512) void k_fused(
    const float* __restrict__ s_buf, const u16* __restrict__ h_buf,
    const float* __restrict__ x, const u16* __restrict__ Bp,
    const u16* __restrict__ xbf,
    const float* __restrict__ bout, float* __restrict__ out)
{
  __shared__ alignas(16) float lists[8 * 64 * 17];   // 8704 floats (34816 B)
  __shared__ float fk[64 * 17];                      // final 16 keys per node
  u16* agg_lds = (u16*)lists;          // [64][136] bf16, bytes [0, 17408)
  float* wk = lists + 4608;            // [64*17] f32 weights, floats [4608, 5696)

  const int lane = threadIdx.x & 63;
  const int w = __builtin_amdgcn_readfirstlane(threadIdx.x >> 6);
  const int g = blockIdx.y;
  const int nb0 = blockIdx.x * 64;
  const int node = g * L + nb0 + lane;

  const float4 si = *(const float4*)(s_buf + (size_t)node * 4);
  const float4* __restrict__ sg = (const float4*)(s_buf + (size_t)g * L * 4);
  const int jb = __builtin_amdgcn_readfirstlane(w * 128);

  float b[16];
#pragma unroll
  for (int k = 0; k < 16; ++k) b[k] = 3.0e38f;

#pragma unroll 4
  for (int j = 0; j < 128; ++j) {
    float4 sj = sg[jb + j];
    float dx = si.x - sj.x, dy = si.y - sj.y;
    float dz = si.z - sj.z, dw2 = si.w - sj.w;
    float d2 = fmaf(dw2, dw2, fmaf(dz, dz, fmaf(dy, dy, dx * dx)));
    u32 db = __float_as_uint(d2);
    float key = __uint_as_float((db & 0xFFFFFC00u) | (u32)(jb + j));
#pragma unroll
    for (int k = 15; k >= 1; --k) b[k] = __builtin_amdgcn_fmed3f(key, b[k - 1], b[k]);
    b[0] = fminf(key, b[0]);
  }

#pragma unroll
  for (int k = 0; k < 16; ++k) lists[(w * 64 + lane) * 17 + k] = b[k];
  __syncthreads();

  float c[16];
  if (w < 4) {
#pragma unroll
    for (int i = 0; i < 16; ++i)
      c[i] = fminf(b[i], lists[((w + 4) * 64 + lane) * 17 + (15 - i)]);
#pragma unroll
    for (int dd = 8; dd >= 1; dd >>= 1) {
#pragma unroll
      for (int i = 0; i < 16; ++i) {
        if ((i & dd) == 0) {
          float lo = fminf(c[i], c[i | dd]);
          float hi = fmaxf(c[i], c[i | dd]);
          c[i] = lo; c[i | dd] = hi;
        }
      }
    }
#pragma unroll
    for (int k = 0; k < 16; ++k) lists[(w * 64 + lane) * 17 + k] = c[k];
  }
  __syncthreads();
  if (w < 2) {
#pragma unroll
    for (int i = 0; i < 16; ++i)
      c[i] = fminf(c[i], lists[((w + 2) * 64 + lane) * 17 + (15 - i)]);
#pragma unroll
    for (int dd = 8; dd >= 1; dd >>= 1) {
#pragma unroll
      for (int i = 0; i < 16; ++i) {
        if ((i & dd) == 0) {
          float lo = fminf(c[i], c[i | dd]);
          float hi = fmaxf(c[i], c[i | dd]);
          c[i] = lo; c[i | dd] = hi;
        }
      }
    }
#pragma unroll
    for (int k = 0; k < 16; ++k) lists[(w * 64 + lane) * 17 + k] = c[k];
  }
  __syncthreads();
  if (w == 0) {
#pragma unroll
    for (int i = 0; i < 16; ++i) {
      float o = lists[(64 + lane) * 17 + (15 - i)];
      float kf = fminf(c[i], o);
      fk[lane * 17 + i] = kf;
      // precomputed edge weight (bit-identical formula to round 2)
      wk[lane * 17 + i] =
          __expf(-10.0f * __uint_as_float(__float_as_uint(kf) & 0xFFFFFC00u));
    }
  }
  __syncthreads();        // fk/wk ready; lists[] selection data dead

  // ---- aggregation: lane <-> (node, 8-dim chunk); no shuffles
  {
    const int q     = lane & 7;              // dim chunk (8 bf16 = 16 B)
    const int nodeL = w * 8 + (lane >> 3);   // 0..63
    const u16* __restrict__ hg = h_buf + (size_t)g * L * FLR;

    float m[8], xx[8];
#pragma unroll
    for (int j = 0; j < 8; ++j) { m[j] = 0.f; xx[j] = -3.0e38f; }

#pragma unroll 4
    for (int k = 0; k < 16; ++k) {
      u32 u    = __float_as_uint(fk[nodeL * 17 + k]);
      float wg = wk[nodeL * 17 + k];
      const uint4 hv = ((const uint4*)(hg + (size_t)(u & 1023u) * FLR))[q];
      u32 p[4] = {hv.x, hv.y, hv.z, hv.w};
#pragma unroll
      for (int d = 0; d < 4; ++d) {
        float lo = __uint_as_float(p[d] << 16) * wg;
        float hi = __uint_as_float(p[d] & 0xFFFF0000u) * wg;
        m[2 * d]     += lo;  xx[2 * d]     = fmaxf(xx[2 * d], lo);
        m[2 * d + 1] += hi;  xx[2 * d + 1] = fmaxf(xx[2 * d + 1], hi);
      }
    }

    uint4 om, ox;
    om.x = pack2(m[0] * 0.0625f, m[1] * 0.0625f);
    om.y = pack2(m[2] * 0.0625f, m[3] * 0.0625f);
    om.z = pack2(m[4] * 0.0625f, m[5] * 0.0625f);
    om.w = pack2(m[6] * 0.0625f, m[7] * 0.0625f);
    ox.x = pack2(xx[0], xx[1]); ox.y = pack2(xx[2], xx[3]);
    ox.z = pack2(xx[4], xx[5]); ox.w = pack2(xx[6], xx[7]);
    *(uint4*)(&agg_lds[nodeL * 136 + q * 8])       = om;
    *(uint4*)(&agg_lds[nodeL * 136 + FLR + q * 8]) = ox;
  }
  __syncthreads();

  // ---- output GEMM
  const int mt  = w & 3;
  const int ntb = (w >> 2) * 4;
  const int rowL = mt * 16 + (lane & 15);
  const int grow = g * L + nb0 + rowL;
  const int kq = (lane >> 4) * 8;

  f32x4 acc[4];
#pragma unroll
  for (int nt = 0; nt < 4; ++nt) acc[nt] = f32x4{0.f, 0.f, 0.f, 0.f};

  const float* xr = x + (size_t)grow * IN;
  const bf16x8* __restrict__ bp = (const bf16x8*)Bp;
  const int tileA = (g * 16 + blockIdx.x) * 4 + mt;

#pragma unroll
  for (int ks = 0; ks < 8; ++ks) {
    bf16x8 a;
    if (ks < 4) {
      if (xbf) {
        a = *(const bf16x8*)(xbf + (((size_t)tileA * 4 + ks) * 64 + lane) * 8);
      } else {
        float4 xa = *(const float4*)(xr + ks * 32 + kq);
        float4 xb = *(const float4*)(xr + ks * 32 + kq + 4);
        union { __hip_bfloat162 h2[4]; bf16x8 v; } cv;
        cv.h2[0] = __float22bfloat162_rn(float2{xa.x, xa.y});
        cv.h2[1] = __float22bfloat162_rn(float2{xa.z, xa.w});
        cv.h2[2] = __float22bfloat162_rn(float2{xb.x, xb.y});
        cv.h2[3] = __float22bfloat162_rn(float2{xb.z, xb.w});
        a = cv.v;
      }
    } else {
      a = *(const bf16x8*)(&agg_lds[rowL * 136 + (ks - 4) * 32 + kq]);
    }
#pragma unroll
    for (int nt = 0; nt < 4; ++nt) {
      bf16x8 bb = bp[((ntb + nt) * 8 + ks) * 64 + lane];
      acc[nt] = __builtin_amdgcn_mfma_f32_16x16x32_bf16(a, bb, acc[nt], 0, 0, 0);
    }
  }

  const int rbase = (lane >> 4) * 4;
  const int col = lane & 15;
  const int mrow = g * L + nb0 + mt * 16;
#pragma unroll
  for (int nt = 0; nt < 4; ++nt) {
    float bias = bout[(ntb + nt) * 16 + col];
#pragma unroll
    for (int r = 0; r < 4; ++r) {
      float v = acc[nt][r] + bias;
      out[(size_t)(mrow + rbase + r) * OUT + (ntb + nt) * 16 + col] = fmaxf(v, 0.0f);
    }
  }
}

extern "C" void kernel_launch(void* const* d_in, const int* in_sizes, int n_in,
                              void* d_out, int out_size, void* d_ws, size_t ws_size,
                              hipStream_t stream) {
  const float* x    = (const float*)d_in[0];
  const float* Ws   = (const float*)d_in[1];
  const float* bs   = (const float*)d_in[2];
  const float* Wh   = (const float*)d_in[3];
  const float* bh   = (const float*)d_in[4];
  const float* Wout = (const float*)d_in[5];
  const float* bout = (const float*)d_in[6];
  float* out = (float*)d_out;

  char* ws = (char*)d_ws;
  float* s_buf = (float*)ws;                                      // 1 MiB
  u16*   h_buf = (u16*)(ws + (1 << 20));                          // 8 MiB
  u16*   Bp    = (u16*)(ws + (1 << 20) + (8 << 20));              // 64 KiB
  u16*   Whp   = (u16*)(ws + (1 << 20) + (8 << 20) + (64 << 10)); // 16 KiB
  // xbf: x in MFMA A-frag bf16 layout, 16 MiB at 10 MiB offset (ws-guarded)
  u16*   xbf   = (ws_size >= (26u << 20)) ? (u16*)(ws + (10 << 20)) : nullptr;

  k_pack<<<17, 256, 0, stream>>>(Wout, Wh, Bp, Whp);
  k_sh<<<N / 64, 256, 0, stream>>>(x, Ws, bs, Whp, bh, s_buf, h_buf, xbf);
  dim3 gknn(L / 64, Bb);
  k_fused<<<gknn, 512, 0, stream>>>(s_buf, h_buf, x, Bp, xbf, bout, out);
}